// Round 4
// baseline (822.129 us; speedup 1.0000x reference)
//
#include <hip/hip_runtime.h>
#include <stdint.h>

#define ENC2   512          // 2*ENC_HID (GEMM K)
#define NDIM   256          // DEC_HID   (GEMM N)
#define BATCH  64
#define SLEN   4096
#define NROWS  (SLEN*BATCH) // GEMM M = 262144
#define BLKR   64           // rows per block (4 waves x 16 rows)
#define NKB    16           // K steps of 32

typedef _Float16 half8 __attribute__((ext_vector_type(8)));
typedef float    f32x4 __attribute__((ext_vector_type(4)));

__device__ __forceinline__ float tanh_fast(float x) {
  float e = __expf(2.0f * x);
  return 1.0f - 2.0f * __builtin_amdgcn_rcpf(e + 1.0f);
}

// Pack We = W[:,256:768] into MFMA B-fragment order (f16):
// wp[((kb*16+ct)*64 + lane)*8 + j] = W[c][256+kk], c=ct*16+(lane&15), kk=kb*32+(lane>>4)*8+j
__global__ __launch_bounds__(256) void pack_We(const float* __restrict__ W,
                                               _Float16* __restrict__ wp) {
  int t = blockIdx.x * 256 + threadIdx.x;   // 0..16383
  int lane = t & 63;
  int ct   = (t >> 6) & 15;
  int kb   = t >> 10;
  int c  = ct * 16 + (lane & 15);
  int kk = kb * 32 + (lane >> 4) * 8;
  const float* src = W + (size_t)c * 768 + 256 + kk;
  half8 h;
#pragma unroll
  for (int j = 0; j < 8; ++j) h[j] = (_Float16)src[j];
  *(half8*)(wp + (size_t)t * 8) = h;
}

// hb[b][k] = bias[k] + sum_d hidden[b][d] * W[k][d]
__global__ __launch_bounds__(256) void compute_hb(const float* __restrict__ hidden,
                                                  const float* __restrict__ W,
                                                  const float* __restrict__ bvec,
                                                  float* __restrict__ hb) {
  __shared__ float hs[256];
  int b = blockIdx.x, k = threadIdx.x;
  hs[k] = hidden[b * 256 + k];
  __syncthreads();
  const float* wr = W + (size_t)k * 768;
  float acc = bvec[k];
#pragma unroll 8
  for (int d = 0; d < 256; d += 4) {
    f32x4 wv = *(const f32x4*)(wr + d);
    acc += wv[0]*hs[d] + wv[1]*hs[d+1] + wv[2]*hs[d+2] + wv[3]*hs[d+3];
  }
  hb[b * 256 + k] = acc;
}

// Fused energy GEMM + tanh + dot(v). No LDS/barriers. Each wave owns 16 rows
// x all 256 cols (acc = 64 VGPRs) so the block fits 128 VGPRs -> 4 waves/SIMD
// (2x the TLP of the 32-row version). B-fragments (packed We, 256 KB,
// L1/L2-resident) read direct from global; A (eo, the HBM stream) is depth-2
// register-prefetched.
__global__ __launch_bounds__(256, 4) void attn_energy(const float* __restrict__ eo,
                                                      const _Float16* __restrict__ wp,
                                                      const float* __restrict__ hb,
                                                      const float* __restrict__ v,
                                                      float* __restrict__ scores) {
  const int tid  = threadIdx.x;
  const int w    = tid >> 6;
  const int lane = tid & 63;
  const int g    = lane >> 4;
  const int l15  = lane & 15;
  const int rowbase = blockIdx.x * BLKR + w * 16;

  // A fragment source: row = rowbase + l15, k-slot start = g*8
  const float* aptr = eo + (size_t)(rowbase + l15) * ENC2 + g * 8;

  f32x4 acc[16];
#pragma unroll
  for (int j = 0; j < 16; ++j) acc[j] = (f32x4){0.f, 0.f, 0.f, 0.f};

#define LDA(v0, v1, KB)                                              \
  do {                                                               \
    const float* p_ = aptr + (size_t)(KB) * 32;                      \
    v0 = *(const f32x4*)(p_);                                        \
    v1 = *(const f32x4*)(p_ + 4);                                    \
  } while (0)

#define CVT(a0, v0, v1)                                              \
  do {                                                               \
    _Pragma("unroll")                                                \
    for (int j = 0; j < 4; ++j) {                                    \
      a0[j] = (_Float16)v0[j]; a0[j + 4] = (_Float16)v1[j];          \
    }                                                                \
  } while (0)

  f32x4 x0, x1;   // A slot even
  f32x4 y0, y1;   // A slot odd
  LDA(x0, x1, 0);
  LDA(y0, y1, 1);

  const half8* bp = (const half8*)wp + lane;

#pragma unroll 1
  for (int kb = 0; kb < NKB; kb += 2) {
    // even step: consume X, refill X with kb+2
    {
      half8 a0;
      CVT(a0, x0, x1);
      if (kb + 2 < NKB) LDA(x0, x1, kb + 2);
      const half8* bpc = bp + (size_t)(kb * 16) * 64;
#pragma unroll
      for (int ct = 0; ct < 16; ++ct) {
        half8 bf = bpc[(size_t)ct * 64];
        acc[ct] = __builtin_amdgcn_mfma_f32_16x16x32_f16(a0, bf, acc[ct], 0, 0, 0);
      }
    }
    // odd step: consume Y, refill Y with kb+3
    {
      half8 a0;
      CVT(a0, y0, y1);
      if (kb + 3 < NKB) LDA(y0, y1, kb + 3);
      const half8* bpc = bp + (size_t)((kb + 1) * 16) * 64;
#pragma unroll
      for (int ct = 0; ct < 16; ++ct) {
        half8 bf = bpc[(size_t)ct * 64];
        acc[ct] = __builtin_amdgcn_mfma_f32_16x16x32_f16(a0, bf, acc[ct], 0, 0, 0);
      }
    }
  }
#undef LDA
#undef CVT

  // epilogue: tanh + dot(v) ; C/D layout: col=lane&15, row=(lane>>4)*4+reg
  float sc[4] = {0.f, 0.f, 0.f, 0.f};
#pragma unroll
  for (int ct = 0; ct < 16; ++ct) {
    int k = ct * 16 + l15;
    float vk = v[k];
    const float* hbk = hb + k;
#pragma unroll
    for (int r = 0; r < 4; ++r) {
      int b0 = (rowbase + g * 4 + r) & 63;
      sc[r] += vk * tanh_fast(acc[ct][r] + hbk[(size_t)b0 * 256]);
    }
  }
#pragma unroll
  for (int m = 1; m < 16; m <<= 1) {
#pragma unroll
    for (int r = 0; r < 4; ++r) sc[r] += __shfl_xor(sc[r], m, 64);
  }
  int r = l15;
  if (r < 4) {
    float o0 = (r == 0) ? sc[0] : (r == 1) ? sc[1] : (r == 2) ? sc[2] : sc[3];
    int gr = rowbase + g * 4 + r;
    scores[(size_t)(gr & 63) * SLEN + (gr >> 6)] = o0;
  }
}

// softmax over s (4096) for each b; out[b][s]
__global__ __launch_bounds__(256) void softmax_rows(const float* __restrict__ scores,
                                                    float* __restrict__ out) {
  int b = blockIdx.x, t = threadIdx.x;
  const f32x4* in4 = (const f32x4*)(scores + (size_t)b * SLEN);
  f32x4* out4 = (f32x4*)(out + (size_t)b * SLEN);
  f32x4 x0 = in4[t], x1 = in4[256 + t], x2 = in4[512 + t], x3 = in4[768 + t];
  float m = fmaxf(fmaxf(fmaxf(x0[0], x0[1]), fmaxf(x0[2], x0[3])),
                  fmaxf(fmaxf(x1[0], x1[1]), fmaxf(x1[2], x1[3])));
  m = fmaxf(m, fmaxf(fmaxf(fmaxf(x2[0], x2[1]), fmaxf(x2[2], x2[3])),
                     fmaxf(fmaxf(x3[0], x3[1]), fmaxf(x3[2], x3[3]))));
#pragma unroll
  for (int off = 1; off < 64; off <<= 1) m = fmaxf(m, __shfl_xor(m, off, 64));
  __shared__ float redm[4], reds[4];
  int w = t >> 6, lane = t & 63;
  if (lane == 0) redm[w] = m;
  __syncthreads();
  m = fmaxf(fmaxf(redm[0], redm[1]), fmaxf(redm[2], redm[3]));
  float s = 0.f;
#pragma unroll
  for (int j = 0; j < 4; ++j) { x0[j] = __expf(x0[j] - m); s += x0[j]; }
#pragma unroll
  for (int j = 0; j < 4; ++j) { x1[j] = __expf(x1[j] - m); s += x1[j]; }
#pragma unroll
  for (int j = 0; j < 4; ++j) { x2[j] = __expf(x2[j] - m); s += x2[j]; }
#pragma unroll
  for (int j = 0; j < 4; ++j) { x3[j] = __expf(x3[j] - m); s += x3[j]; }
#pragma unroll
  for (int off = 1; off < 64; off <<= 1) s += __shfl_xor(s, off, 64);
  if (lane == 0) reds[w] = s;
  __syncthreads();
  s = (reds[0] + reds[1]) + (reds[2] + reds[3]);
  float inv = 1.0f / s;
#pragma unroll
  for (int j = 0; j < 4; ++j) { x0[j] *= inv; x1[j] *= inv; x2[j] *= inv; x3[j] *= inv; }
  out4[t] = x0; out4[256 + t] = x1; out4[512 + t] = x2; out4[768 + t] = x3;
}

extern "C" void kernel_launch(void* const* d_in, const int* in_sizes, int n_in,
                              void* d_out, int out_size, void* d_ws, size_t ws_size,
                              hipStream_t stream) {
  (void)in_sizes; (void)n_in; (void)out_size; (void)ws_size;
  const float* hidden = (const float*)d_in[0];  // (1,64,256)
  const float* eo     = (const float*)d_in[1];  // (4096,64,512)
  const float* W      = (const float*)d_in[2];  // (256,768)
  const float* bvec   = (const float*)d_in[3];  // (256,)
  const float* v      = (const float*)d_in[4];  // (256,)
  float* out = (float*)d_out;                   // (64,4096)

  uint8_t* ws = (uint8_t*)d_ws;
  _Float16* wp  = (_Float16*)ws;                      // 256 KB packed We (f16)
  float* hb     = (float*)(ws + 262144);              // 64 KB hb[b][k]
  float* scores = (float*)(ws + 262144 + 65536);      // 1 MB scores[b][s]

  pack_We<<<64, 256, 0, stream>>>(W, wp);
  compute_hb<<<64, 256, 0, stream>>>(hidden, W, bvec, hb);
  attn_energy<<<NROWS / BLKR, 256, 0, stream>>>(eo, wp, hb, v, scores);
  softmax_rows<<<BATCH, 256, 0, stream>>>(scores, out);
}

// Round 6
// 759.997 us; speedup vs baseline: 1.0818x; 1.0818x over previous
//
#include <hip/hip_runtime.h>
#include <stdint.h>

#define ENC2   512          // 2*ENC_HID (GEMM K)
#define NDIM   256          // DEC_HID   (GEMM N)
#define BATCH  64
#define SLEN   4096
#define NROWS  (SLEN*BATCH) // GEMM M = 262144
#define BLKR   128          // rows per block
#define NKB    16           // K steps of 32

typedef _Float16 half8 __attribute__((ext_vector_type(8)));
typedef float    f32x4 __attribute__((ext_vector_type(4)));

__device__ __forceinline__ float tanh_fast(float x) {
  float e = __expf(2.0f * x);
  return 1.0f - 2.0f * __builtin_amdgcn_rcpf(e + 1.0f);
}

__device__ __forceinline__ void gld_lds16(const _Float16* g, _Float16* l) {
  __builtin_amdgcn_global_load_lds(
      (const __attribute__((address_space(1))) void*)g,
      (__attribute__((address_space(3))) void*)l, 16, 0, 0);
}

// Merged prep: blocks 0..63 compute hb[b][k]; blocks 64..127 pack We.
// pack: wp[((kb*16+ct)*64 + lane)*8 + j] = W[c][256+kk],
//       c=ct*16+(lane&15), kk=kb*32+(lane>>4)*8+j
__global__ __launch_bounds__(256) void prep(const float* __restrict__ hidden,
                                            const float* __restrict__ W,
                                            const float* __restrict__ bvec,
                                            float* __restrict__ hb,
                                            _Float16* __restrict__ wp) {
  __shared__ float hs[256];
  if (blockIdx.x < 64) {
    int b = blockIdx.x, k = threadIdx.x;
    hs[k] = hidden[b * 256 + k];
    __syncthreads();
    const float* wr = W + (size_t)k * 768;
    float acc = bvec[k];
#pragma unroll 8
    for (int d = 0; d < 256; d += 4) {
      f32x4 wv = *(const f32x4*)(wr + d);
      acc += wv[0]*hs[d] + wv[1]*hs[d+1] + wv[2]*hs[d+2] + wv[3]*hs[d+3];
    }
    hb[b * 256 + k] = acc;
  } else {
    int t = (blockIdx.x - 64) * 256 + threadIdx.x;   // 0..16383
    int lane = t & 63;
    int ct   = (t >> 6) & 15;
    int kb   = t >> 10;
    int c  = ct * 16 + (lane & 15);
    int kk = kb * 32 + (lane >> 4) * 8;
    const float* src = W + (size_t)c * 768 + 256 + kk;
    half8 h;
#pragma unroll
    for (int j = 0; j < 8; ++j) h[j] = (_Float16)src[j];
    *(half8*)(wp + (size_t)t * 8) = h;
  }
}

// Fused: scores[b][s] = sum_k v[k] * tanh(hb[b][k] + sum_e eo[row][e]*We[k][e]),
// row = s*64+b (natural encoder_outputs layout). B staged block-shared in LDS
// (double-buffered, global_load_lds w=16) -> B L2 traffic = 0.5 GB total,
// the minimum measured configuration (R0 = 763 us vs 778/822 for no-LDS).
__global__ __launch_bounds__(256) void attn_energy(const float* __restrict__ eo,
                                                   const _Float16* __restrict__ wp,
                                                   const float* __restrict__ hb,
                                                   const float* __restrict__ v,
                                                   float* __restrict__ scores) {
  __shared__ _Float16 lds[2][8192];   // 2 x 16 KB B-tiles
  const int tid  = threadIdx.x;
  const int w    = tid >> 6;
  const int lane = tid & 63;
  const int g    = lane >> 4;
  const int l15  = lane & 15;
  const int rowbase = blockIdx.x * BLKR + w * 32;

  // A fragment source: row = rowbase + rt*16 + l15, k-slot start = g*8
  const float* aptr0 = eo + (size_t)(rowbase + l15) * ENC2 + g * 8;
  const float* aptr1 = aptr0 + 16 * ENC2;

  f32x4 acc[2][16];
#pragma unroll
  for (int i = 0; i < 2; ++i)
#pragma unroll
    for (int j = 0; j < 16; ++j) acc[i][j] = (f32x4){0.f, 0.f, 0.f, 0.f};

  // prologue: stage B(kb=0) into buf0; load A(kb=0)
  {
    const _Float16* src = wp + (size_t)(w * 4) * 512 + lane * 8;
    _Float16* dst = &lds[0][(w * 4) * 512];
#pragma unroll
    for (int i = 0; i < 4; ++i) gld_lds16(src + i * 512, dst + i * 512);
  }
  f32x4 ar00 = *(const f32x4*)(aptr0);
  f32x4 ar01 = *(const f32x4*)(aptr0 + 4);
  f32x4 ar10 = *(const f32x4*)(aptr1);
  f32x4 ar11 = *(const f32x4*)(aptr1 + 4);
  __syncthreads();

  int cur = 0;
#pragma unroll 1
  for (int kb = 0; kb < NKB; ++kb) {
    half8 a0, a1;
#pragma unroll
    for (int j = 0; j < 4; ++j) {
      a0[j]     = (_Float16)ar00[j];
      a0[j + 4] = (_Float16)ar01[j];
      a1[j]     = (_Float16)ar10[j];
      a1[j + 4] = (_Float16)ar11[j];
    }
    if (kb < NKB - 1) {   // prefetch next K-step (B -> LDS other buf, A -> regs)
      const _Float16* src = wp + (size_t)(kb + 1) * 8192 + (w * 4) * 512 + lane * 8;
      _Float16* dst = &lds[cur ^ 1][(w * 4) * 512];
#pragma unroll
      for (int i = 0; i < 4; ++i) gld_lds16(src + i * 512, dst + i * 512);
      const float* p0 = aptr0 + (size_t)(kb + 1) * 32;
      const float* p1 = aptr1 + (size_t)(kb + 1) * 32;
      ar00 = *(const f32x4*)(p0);
      ar01 = *(const f32x4*)(p0 + 4);
      ar10 = *(const f32x4*)(p1);
      ar11 = *(const f32x4*)(p1 + 4);
    }
    const _Float16* bufc = &lds[cur][lane * 8];
#pragma unroll
    for (int ct = 0; ct < 16; ++ct) {
      half8 bf = *(const half8*)(bufc + ct * 512);
      acc[0][ct] = __builtin_amdgcn_mfma_f32_16x16x32_f16(a0, bf, acc[0][ct], 0, 0, 0);
      acc[1][ct] = __builtin_amdgcn_mfma_f32_16x16x32_f16(a1, bf, acc[1][ct], 0, 0, 0);
    }
    __syncthreads();
    cur ^= 1;
  }

  // epilogue: tanh + dot(v) ; C/D layout: col=lane&15, row=(lane>>4)*4+reg
  float sc0[4] = {0.f, 0.f, 0.f, 0.f};
  float sc1[4] = {0.f, 0.f, 0.f, 0.f};
#pragma unroll
  for (int ct = 0; ct < 16; ++ct) {
    int k = ct * 16 + l15;
    float vk = v[k];
    const float* hbk = hb + k;
#pragma unroll
    for (int r = 0; r < 4; ++r) {
      int b0 = (rowbase + g * 4 + r) & 63;
      int b1 = (rowbase + 16 + g * 4 + r) & 63;
      sc0[r] += vk * tanh_fast(acc[0][ct][r] + hbk[(size_t)b0 * 256]);
      sc1[r] += vk * tanh_fast(acc[1][ct][r] + hbk[(size_t)b1 * 256]);
    }
  }
#pragma unroll
  for (int m = 1; m < 16; m <<= 1) {
#pragma unroll
    for (int r = 0; r < 4; ++r) {
      sc0[r] += __shfl_xor(sc0[r], m, 64);
      sc1[r] += __shfl_xor(sc1[r], m, 64);
    }
  }
  int r = l15;
  if (r < 4) {
    float o0 = (r == 0) ? sc0[0] : (r == 1) ? sc0[1] : (r == 2) ? sc0[2] : sc0[3];
    float o1 = (r == 0) ? sc1[0] : (r == 1) ? sc1[1] : (r == 2) ? sc1[2] : sc1[3];
    int gr0 = rowbase + g * 4 + r;
    int gr1 = rowbase + 16 + g * 4 + r;
    scores[(size_t)(gr0 & 63) * SLEN + (gr0 >> 6)] = o0;
    scores[(size_t)(gr1 & 63) * SLEN + (gr1 >> 6)] = o1;
  }
}

// softmax over s (4096) for each b; out[b][s]
__global__ __launch_bounds__(256) void softmax_rows(const float* __restrict__ scores,
                                                    float* __restrict__ out) {
  int b = blockIdx.x, t = threadIdx.x;
  const f32x4* in4 = (const f32x4*)(scores + (size_t)b * SLEN);
  f32x4* out4 = (f32x4*)(out + (size_t)b * SLEN);
  f32x4 x0 = in4[t], x1 = in4[256 + t], x2 = in4[512 + t], x3 = in4[768 + t];
  float m = fmaxf(fmaxf(fmaxf(x0[0], x0[1]), fmaxf(x0[2], x0[3])),
                  fmaxf(fmaxf(x1[0], x1[1]), fmaxf(x1[2], x1[3])));
  m = fmaxf(m, fmaxf(fmaxf(fmaxf(x2[0], x2[1]), fmaxf(x2[2], x2[3])),
                     fmaxf(fmaxf(x3[0], x3[1]), fmaxf(x3[2], x3[3]))));
#pragma unroll
  for (int off = 1; off < 64; off <<= 1) m = fmaxf(m, __shfl_xor(m, off, 64));
  __shared__ float redm[4], reds[4];
  int w = t >> 6, lane = t & 63;
  if (lane == 0) redm[w] = m;
  __syncthreads();
  m = fmaxf(fmaxf(redm[0], redm[1]), fmaxf(redm[2], redm[3]));
  float s = 0.f;
#pragma unroll
  for (int j = 0; j < 4; ++j) { x0[j] = __expf(x0[j] - m); s += x0[j]; }
#pragma unroll
  for (int j = 0; j < 4; ++j) { x1[j] = __expf(x1[j] - m); s += x1[j]; }
#pragma unroll
  for (int j = 0; j < 4; ++j) { x2[j] = __expf(x2[j] - m); s += x2[j]; }
#pragma unroll
  for (int j = 0; j < 4; ++j) { x3[j] = __expf(x3[j] - m); s += x3[j]; }
#pragma unroll
  for (int off = 1; off < 64; off <<= 1) s += __shfl_xor(s, off, 64);
  if (lane == 0) reds[w] = s;
  __syncthreads();
  s = (reds[0] + reds[1]) + (reds[2] + reds[3]);
  float inv = 1.0f / s;
#pragma unroll
  for (int j = 0; j < 4; ++j) { x0[j] *= inv; x1[j] *= inv; x2[j] *= inv; x3[j] *= inv; }
  out4[t] = x0; out4[256 + t] = x1; out4[512 + t] = x2; out4[768 + t] = x3;
}

extern "C" void kernel_launch(void* const* d_in, const int* in_sizes, int n_in,
                              void* d_out, int out_size, void* d_ws, size_t ws_size,
                              hipStream_t stream) {
  (void)in_sizes; (void)n_in; (void)out_size; (void)ws_size;
  const float* hidden = (const float*)d_in[0];  // (1,64,256)
  const float* eo     = (const float*)d_in[1];  // (4096,64,512)
  const float* W      = (const float*)d_in[2];  // (256,768)
  const float* bvec   = (const float*)d_in[3];  // (256,)
  const float* v      = (const float*)d_in[4];  // (256,)
  float* out = (float*)d_out;                   // (64,4096)

  uint8_t* ws = (uint8_t*)d_ws;
  _Float16* wp  = (_Float16*)ws;                      // 256 KB packed We (f16)
  float* hb     = (float*)(ws + 262144);              // 64 KB hb[b][k]
  float* scores = (float*)(ws + 262144 + 65536);      // 1 MB scores[b][s]

  prep<<<128, 256, 0, stream>>>(hidden, W, bvec, hb, wp);
  attn_energy<<<NROWS / BLKR, 256, 0, stream>>>(eo, wp, hb, v, scores);
  softmax_rows<<<BATCH, 256, 0, stream>>>(scores, out);
}